// Round 1
// baseline (914.161 us; speedup 1.0000x reference)
//
#include <hip/hip_runtime.h>

#define EPS_BN 1e-5f

// ---------------------------------------------------------------------------
// Direct 3x3 SAME conv, one block per (n, c_out). Optionally applies BN+ReLU
// of the *previous* layer to its input while staging into LDS (scale/shift
// computed from accumulated sum/sumsq), and optionally accumulates this
// layer's BN statistics (sum, sumsq per channel) via atomics.
// Thread mapping: 256 threads, thread t computes row r=t>>3, cols (t&7)*4..+3.
// LDS tile stride 37: (37r + 4k + j) mod 32 gives exactly 2 lanes/bank (free).
// ---------------------------------------------------------------------------
template<int CIN, int COUT, bool BN_IN, bool STATS>
__global__ __launch_bounds__(256) void conv3x3_kern(
    const float* __restrict__ in,        // (4,CIN,32,32) raw pre-BN values
    const float* __restrict__ wgt,       // (COUT,CIN,3,3)
    const float* __restrict__ bias,      // (COUT)
    const float* __restrict__ in_stats,  // (2,64): sum, sumsq of input layer
    const float* __restrict__ gamma,     // (64) BN params of input layer
    const float* __restrict__ beta,
    float* __restrict__ out,             // (4,COUT,32,32)
    float* __restrict__ out_stats)       // (2,COUT) accumulated
{
    constexpr int TS = 37;               // tile row stride (34 cols used)
    __shared__ float tile[34 * TS];
    __shared__ float s_scale[64];
    __shared__ float s_shift[64];

    const int tid = threadIdx.x;
    const int n   = blockIdx.x / COUT;
    const int co  = blockIdx.x - n * COUT;

    if (BN_IN) {
        if (tid < CIN) {
            float s    = in_stats[tid];
            float ss   = in_stats[64 + tid];
            float mean = s * (1.0f / 4096.0f);
            float var  = fmaxf(ss * (1.0f / 4096.0f) - mean * mean, 0.0f);
            float g    = gamma[tid] * rsqrtf(var + EPS_BN);
            s_scale[tid] = g;
            s_shift[tid] = beta[tid] - mean * g;
        }
        __syncthreads();
    }

    const int r  = tid >> 3;
    const int c4 = (tid & 7) << 2;

    float acc[4] = {0.f, 0.f, 0.f, 0.f};

    for (int ci = 0; ci < CIN; ++ci) {
        const float* ip = in + ((n * CIN + ci) << 10);
        float sc = 1.f, sh = 0.f;
        if (BN_IN) { sc = s_scale[ci]; sh = s_shift[ci]; }
        // stage 34x34 (stride 37) plane with zero halo; BN+ReLU on the fly.
        for (int e = tid; e < 34 * TS; e += 256) {
            int rr = e / TS;
            int cc = e - rr * TS;
            int ir = rr - 1, ic = cc - 1;
            float v = 0.f;
            if ((unsigned)ir < 32u && (unsigned)ic < 32u) {
                v = ip[(ir << 5) + ic];
                if (BN_IN) v = fmaxf(fmaf(sc, v, sh), 0.f);
            }
            tile[e] = v;
        }
        __syncthreads();

        const float* wp = wgt + (co * CIN + ci) * 9;  // block-uniform -> s_load
        float w0=wp[0], w1=wp[1], w2=wp[2], w3=wp[3], w4=wp[4],
              w5=wp[5], w6=wp[6], w7=wp[7], w8=wp[8];

        #pragma unroll
        for (int dr = 0; dr < 3; ++dr) {
            const float* tr = &tile[(r + dr) * TS + c4];
            float t0=tr[0], t1=tr[1], t2=tr[2], t3=tr[3], t4=tr[4], t5=tr[5];
            float wa = (dr == 0) ? w0 : ((dr == 1) ? w3 : w6);
            float wb = (dr == 0) ? w1 : ((dr == 1) ? w4 : w7);
            float wc = (dr == 0) ? w2 : ((dr == 1) ? w5 : w8);
            acc[0] = fmaf(wa, t0, fmaf(wb, t1, fmaf(wc, t2, acc[0])));
            acc[1] = fmaf(wa, t1, fmaf(wb, t2, fmaf(wc, t3, acc[1])));
            acc[2] = fmaf(wa, t2, fmaf(wb, t3, fmaf(wc, t4, acc[2])));
            acc[3] = fmaf(wa, t3, fmaf(wb, t4, fmaf(wc, t5, acc[3])));
        }
        __syncthreads();
    }

    float b = bias[co];
    float4 res;
    res.x = acc[0] + b; res.y = acc[1] + b;
    res.z = acc[2] + b; res.w = acc[3] + b;
    float* op = out + ((n * COUT + co) << 10) + (r << 5) + c4;
    *(float4*)op = res;

    if (STATS) {
        float s  = res.x + res.y + res.z + res.w;
        float ss = res.x*res.x + res.y*res.y + res.z*res.z + res.w*res.w;
        #pragma unroll
        for (int off = 32; off; off >>= 1) {
            s  += __shfl_down(s,  off);
            ss += __shfl_down(ss, off);
        }
        if ((tid & 63) == 0) {
            atomicAdd(&out_stats[co],      s);
            atomicAdd(&out_stats[64 + co], ss);
        }
    }
}

// ---------------------------------------------------------------------------
// Hadamard attention. One block per (t, i) row; the att_w row (4 KB) is read
// once and reused for all 4 batch images. xf rows for all 4 n staged in LDS.
// Writes the 1024-wide softmax row (att output) and the weighted sum (out).
// ---------------------------------------------------------------------------
__global__ __launch_bounds__(256) void attention_kern(
    const float* __restrict__ xf,     // (4,12,1024)
    const float* __restrict__ att_w,  // (12,1024,1024)
    float* __restrict__ out,          // (4,12,1024)
    float* __restrict__ att)          // (4,12,1024,1024)
{
    __shared__ __align__(16) float s_xf[4096];
    __shared__ float red[8];
    const int tid = threadIdx.x;
    const int t   = blockIdx.x >> 10;
    const int i   = blockIdx.x & 1023;
    const int w   = tid >> 6;

    // stage xf for all 4 images of timestep t
    const float4* xf4 = (const float4*)xf;
    float4* s4 = (float4*)s_xf;
    #pragma unroll
    for (int q = 0; q < 4; ++q) {
        int e  = tid + (q << 8);      // float4 index within (4,1024)
        int nn = e >> 8;
        int j4 = e & 255;
        s4[e] = xf4[((nn * 12 + t) << 8) + j4];
    }
    float4 wv = ((const float4*)att_w)[(((t << 10) + i) << 8) + tid];
    __syncthreads();

    #pragma unroll 1
    for (int nn = 0; nn < 4; ++nn) {
        float4 xv = ((const float4*)(s_xf + (nn << 10)))[tid];
        float s0 = wv.x * xv.x, s1 = wv.y * xv.y,
              s2 = wv.z * xv.z, s3 = wv.w * xv.w;

        // block max
        float m = fmaxf(fmaxf(s0, s1), fmaxf(s2, s3));
        #pragma unroll
        for (int off = 32; off; off >>= 1) m = fmaxf(m, __shfl_down(m, off));
        if ((tid & 63) == 0) red[w] = m;
        __syncthreads();
        m = fmaxf(fmaxf(red[0], red[1]), fmaxf(red[2], red[3]));

        float e0 = __expf(s0 - m), e1 = __expf(s1 - m),
              e2 = __expf(s2 - m), e3 = __expf(s3 - m);
        float ps = e0 + e1 + e2 + e3;
        float pd = e0*xv.x + e1*xv.y + e2*xv.z + e3*xv.w;
        #pragma unroll
        for (int off = 32; off; off >>= 1) {
            ps += __shfl_down(ps, off);
            pd += __shfl_down(pd, off);
        }
        __syncthreads();              // everyone done reading red (max)
        if ((tid & 63) == 0) { red[w] = ps; red[4 + w] = pd; }
        __syncthreads();
        float sum = red[0] + red[1] + red[2] + red[3];
        float dot = red[4] + red[5] + red[6] + red[7];
        float inv = 1.0f / sum;

        float4 av;
        av.x = e0 * inv; av.y = e1 * inv; av.z = e2 * inv; av.w = e3 * inv;
        ((float4*)att)[((((nn * 12 + t) << 10) + i) << 8) + tid] = av;
        if (tid == 0) out[((nn * 12 + t) << 10) + i] = dot * inv;
        __syncthreads();              // red reused next iteration
    }
}

extern "C" void kernel_launch(void* const* d_in, const int* in_sizes, int n_in,
                              void* d_out, int out_size, void* d_ws, size_t ws_size,
                              hipStream_t stream)
{
    const float* x      = (const float*)d_in[0];
    const float* conv0w = (const float*)d_in[1];  // (64,12,3,3)
    const float* convw  = (const float*)d_in[2];  // (4,64,64,3,3)
    const float* convb  = (const float*)d_in[3];  // (5,64)
    const float* gammas = (const float*)d_in[4];  // (5,64)
    const float* betas  = (const float*)d_in[5];  // (5,64)
    const float* regw   = (const float*)d_in[6];  // (12,64,3,3)
    const float* regb   = (const float*)d_in[7];  // (12)
    const float* attw   = (const float*)d_in[8];  // (12,1024,1024)

    float* out = (float*)d_out;                   // (4,12,32,32) = 49152
    float* att = out + 4 * 12 * 1024;             // (4,12,1024,1024)

    float* ws    = (float*)d_ws;
    float* stats = ws;                            // 5 layers x 128 floats
    float* bufA  = ws + 1024;                     // (4,64,32,32)
    float* bufB  = bufA + 262144;                 // (4,64,32,32)
    float* xf    = bufB + 262144;                 // (4,12,1024)

    hipMemsetAsync(stats, 0, 5 * 128 * sizeof(float), stream);

    // conv0: 12 -> 64, raw input, accumulate stats0
    conv3x3_kern<12, 64, false, true><<<256, 256, 0, stream>>>(
        x, conv0w, convb, nullptr, nullptr, nullptr, bufA, stats);
    // conv1..conv4: 64 -> 64, BN(prev)+ReLU on input, accumulate own stats
    conv3x3_kern<64, 64, true, true><<<256, 256, 0, stream>>>(
        bufA, convw + 0 * 36864, convb + 64, stats, gammas, betas,
        bufB, stats + 128);
    conv3x3_kern<64, 64, true, true><<<256, 256, 0, stream>>>(
        bufB, convw + 1 * 36864, convb + 128, stats + 128, gammas + 64, betas + 64,
        bufA, stats + 256);
    conv3x3_kern<64, 64, true, true><<<256, 256, 0, stream>>>(
        bufA, convw + 2 * 36864, convb + 192, stats + 256, gammas + 128, betas + 128,
        bufB, stats + 384);
    conv3x3_kern<64, 64, true, true><<<256, 256, 0, stream>>>(
        bufB, convw + 3 * 36864, convb + 256, stats + 384, gammas + 192, betas + 192,
        bufA, stats + 512);
    // regressor conv: 64 -> 12, BN(layer4)+ReLU on input, no stats
    conv3x3_kern<64, 12, true, false><<<48, 256, 0, stream>>>(
        bufA, regw, regb, stats + 512, gammas + 256, betas + 256, xf, nullptr);

    attention_kern<<<12288, 256, 0, stream>>>(xf, attw, out, att);
}

// Round 3
// 401.547 us; speedup vs baseline: 2.2766x; 2.2766x over previous
//
#include <hip/hip_runtime.h>

#define EPS_BN 1e-5f

typedef float f32x4 __attribute__((ext_vector_type(4)));

// Padded plane geometry: logical rows -1..32 at index r+1 (34 rows),
// logical cols -1..34 at index c+1 (36 cols). Reading 6 cols starting at
// logical col c4-1 begins at index c4 -> 16B aligned (c4 multiple of 4).
#define PROWS 34
#define PCOLS 36
#define PS (PROWS * PCOLS)   // 1224 floats per plane

// ---------------------------------------------------------------------------
// Copy raw (P,32,32) input into padded (P,34,36) buffer (borders pre-zeroed
// by the launch-time memset).
// ---------------------------------------------------------------------------
__global__ __launch_bounds__(256) void pad_copy_kern(
    const float* __restrict__ x, float* __restrict__ bufX)
{
    const int plane = blockIdx.x;
    const int tid = threadIdx.x;
    const int r  = tid >> 3;
    const int c4 = (tid & 7) << 2;
    float4 v = *(const float4*)(x + (plane << 10) + (r << 5) + c4);
    float* o = bufX + plane * PS + (r + 1) * PCOLS + (c4 + 1);
    o[0] = v.x; o[1] = v.y; o[2] = v.z; o[3] = v.w;
}

// ---------------------------------------------------------------------------
// Direct 3x3 SAME conv, one block per (n, co), 256 threads, thread = 4-px
// horizontal strip (r = tid>>3, cols c4..c4+3). No LDS tile, no per-ci
// barriers: reads padded global planes with aligned float4/float2 loads;
// ci-loop iterations are independent -> ILP hides L1/L2 latency.
//
// BN_IN: input buffer holds RAW pre-BN values (zero pads); we apply
// h = relu(sc*x+sh) inline. Pads then wrongly contribute w*relu(sh); a
// per-(co,border-class) correction (8 scalars, wave-0 prologue) fixes it.
// STATS: accumulate this layer's per-channel sum/sumsq via atomics.
// PAD_OUT: write raw output into padded buffer interior; else flat (1024).
// ---------------------------------------------------------------------------
template<int CIN, int COUT, bool BN_IN, bool STATS, bool PAD_OUT>
__global__ __launch_bounds__(256) void conv3x3_v2(
    const float* __restrict__ in,        // padded (4,CIN,34,36) raw values
    const float* __restrict__ wgt,       // (COUT,CIN,3,3)
    const float* __restrict__ bias,      // (COUT)
    const float* __restrict__ in_stats,  // (2,64) sum,sumsq of input layer
    const float* __restrict__ gamma,     // (64) BN params of input layer
    const float* __restrict__ beta,
    float* __restrict__ out,
    float* __restrict__ out_stats)       // (2,COUT)
{
    __shared__ float s_sc[64];
    __shared__ float s_sh[64];
    __shared__ float s_corr[8];          // T,B,L,R,TL,TR,BL,BR

    const int tid = threadIdx.x;
    const int n   = blockIdx.x / COUT;
    const int co  = blockIdx.x - n * COUT;

    if (BN_IN) {
        if (tid < CIN) {                 // CIN==64 here -> exactly wave 0
            float s    = in_stats[tid];
            float ss   = in_stats[64 + tid];
            float mean = s * (1.0f / 4096.0f);
            float var  = fmaxf(ss * (1.0f / 4096.0f) - mean * mean, 0.0f);
            float g    = gamma[tid] * rsqrtf(var + EPS_BN);
            float sc   = g;
            float sh   = beta[tid] - mean * g;
            s_sc[tid] = sc;
            s_sh[tid] = sh;
            // border-correction partials: rl = value a zero-pad tap produces
            float rl = fmaxf(sh, 0.0f);
            const float* wp = wgt + (co * CIN + tid) * 9;
            float w0=wp[0], w1=wp[1], w2=wp[2], w3=wp[3],
                  w5=wp[5], w6=wp[6], w7=wp[7], w8=wp[8];
            float pT  = rl * (w0 + w1 + w2);
            float pB  = rl * (w6 + w7 + w8);
            float pL  = rl * (w0 + w3 + w6);
            float pR  = rl * (w2 + w5 + w8);
            float pTL = rl * w0, pTR = rl * w2, pBL = rl * w6, pBR = rl * w8;
            #pragma unroll
            for (int off = 32; off; off >>= 1) {
                pT  += __shfl_down(pT,  off); pB  += __shfl_down(pB,  off);
                pL  += __shfl_down(pL,  off); pR  += __shfl_down(pR,  off);
                pTL += __shfl_down(pTL, off); pTR += __shfl_down(pTR, off);
                pBL += __shfl_down(pBL, off); pBR += __shfl_down(pBR, off);
            }
            if (tid == 0) {
                s_corr[0]=pT; s_corr[1]=pB; s_corr[2]=pL; s_corr[3]=pR;
                s_corr[4]=pTL; s_corr[5]=pTR; s_corr[6]=pBL; s_corr[7]=pBR;
            }
        }
        __syncthreads();
    }

    const int r  = tid >> 3;             // 0..31
    const int c4 = (tid & 7) << 2;       // 0,4,..,28
    // points at padded (row r-1, col c4-1) = index (r, c4)
    const float* ip = in + n * CIN * PS + r * PCOLS + c4;

    float acc0 = 0.f, acc1 = 0.f, acc2 = 0.f, acc3 = 0.f;

    #pragma unroll 2
    for (int ci = 0; ci < CIN; ++ci) {
        const float* p  = ip + ci * PS;
        const float* wp = wgt + (co * CIN + ci) * 9;   // block-uniform
        float sc = 0.f, sh = 0.f;
        if (BN_IN) { sc = s_sc[ci]; sh = s_sh[ci]; }
        #pragma unroll
        for (int dr = 0; dr < 3; ++dr) {
            float4 a = *(const float4*)(p + dr * PCOLS);
            float2 b = *(const float2*)(p + dr * PCOLS + 4);
            float h0, h1, h2, h3, h4, h5;
            if (BN_IN) {
                h0 = fmaxf(fmaf(sc, a.x, sh), 0.f);
                h1 = fmaxf(fmaf(sc, a.y, sh), 0.f);
                h2 = fmaxf(fmaf(sc, a.z, sh), 0.f);
                h3 = fmaxf(fmaf(sc, a.w, sh), 0.f);
                h4 = fmaxf(fmaf(sc, b.x, sh), 0.f);
                h5 = fmaxf(fmaf(sc, b.y, sh), 0.f);
            } else {
                h0 = a.x; h1 = a.y; h2 = a.z; h3 = a.w; h4 = b.x; h5 = b.y;
            }
            float wa = wp[dr * 3 + 0], wb = wp[dr * 3 + 1], wc = wp[dr * 3 + 2];
            acc0 = fmaf(wa, h0, fmaf(wb, h1, fmaf(wc, h2, acc0)));
            acc1 = fmaf(wa, h1, fmaf(wb, h2, fmaf(wc, h3, acc1)));
            acc2 = fmaf(wa, h2, fmaf(wb, h3, fmaf(wc, h4, acc2)));
            acc3 = fmaf(wa, h3, fmaf(wb, h4, fmaf(wc, h5, acc3)));
        }
    }

    float bv = bias[co];
    float u0 = acc0 + bv, u1 = acc1 + bv, u2 = acc2 + bv, u3 = acc3 + bv;

    if (BN_IN) {
        // subtract spurious pad contributions (w * relu(sh) per missing tap)
        float corr = (r == 0 ? s_corr[0] : 0.f) + (r == 31 ? s_corr[1] : 0.f);
        u0 -= corr; u1 -= corr; u2 -= corr; u3 -= corr;
        if (c4 == 0) {
            u0 -= s_corr[2];
            if (r == 0)  u0 += s_corr[4];
            if (r == 31) u0 += s_corr[6];
        }
        if (c4 == 28) {
            u3 -= s_corr[3];
            if (r == 0)  u3 += s_corr[5];
            if (r == 31) u3 += s_corr[7];
        }
    }

    if (PAD_OUT) {
        float* op = out + (n * COUT + co) * PS + (r + 1) * PCOLS + (c4 + 1);
        op[0] = u0; op[1] = u1; op[2] = u2; op[3] = u3;
    } else {
        float4 res; res.x = u0; res.y = u1; res.z = u2; res.w = u3;
        *(float4*)(out + ((n * COUT + co) << 10) + (r << 5) + c4) = res;
    }

    if (STATS) {
        float s  = u0 + u1 + u2 + u3;
        float ss = u0*u0 + u1*u1 + u2*u2 + u3*u3;
        #pragma unroll
        for (int off = 32; off; off >>= 1) {
            s  += __shfl_down(s,  off);
            ss += __shfl_down(ss, off);
        }
        if ((tid & 63) == 0) {
            atomicAdd(&out_stats[co],      s);
            atomicAdd(&out_stats[64 + co], ss);
        }
    }
}

// ---------------------------------------------------------------------------
// Hadamard attention. One block per (t,i); att_w row read once, reused for
// all 4 batch images. No max-subtraction (|scores| < 1 by construction:
// |att_w| <= 0.054 xavier limit, |xf| ~ O(5)), so a single fused
// sum/dot reduction round suffices (2 barriers total). att written with
// nontemporal native-vector stores (201 MB, never re-read).
// ---------------------------------------------------------------------------
__global__ __launch_bounds__(256) void attention_v2(
    const float* __restrict__ xf,     // (4,12,1024)
    const float* __restrict__ att_w,  // (12,1024,1024)
    float* __restrict__ out,          // (4,12,1024)
    float* __restrict__ att)          // (4,12,1024,1024)
{
    __shared__ __align__(16) float s_xf[4096];
    __shared__ float red[4][8];       // [wave][ps0..3, pd0..3]
    const int tid = threadIdx.x;
    const int t   = blockIdx.x >> 10;
    const int i   = blockIdx.x & 1023;
    const int w   = tid >> 6;

    const float4* xf4 = (const float4*)xf;
    float4* s4 = (float4*)s_xf;
    #pragma unroll
    for (int q = 0; q < 4; ++q) {
        int e  = (q << 8) + tid;
        int nn = e >> 8;
        int j4 = e & 255;
        s4[e] = xf4[((nn * 12 + t) << 8) + j4];
    }
    float4 wv = ((const float4*)att_w)[(((t << 10) + i) << 8) + tid];
    __syncthreads();

    float ev[4][4], ps[4], pd[4];
    #pragma unroll
    for (int nn = 0; nn < 4; ++nn) {
        float4 xv = ((const float4*)(s_xf + (nn << 10)))[tid];
        float e0 = __expf(wv.x * xv.x);
        float e1 = __expf(wv.y * xv.y);
        float e2 = __expf(wv.z * xv.z);
        float e3 = __expf(wv.w * xv.w);
        ps[nn] = (e0 + e1) + (e2 + e3);
        pd[nn] = fmaf(e0, xv.x, fmaf(e1, xv.y, fmaf(e2, xv.z, e3 * xv.w)));
        ev[nn][0] = e0; ev[nn][1] = e1; ev[nn][2] = e2; ev[nn][3] = e3;
    }
    #pragma unroll
    for (int off = 32; off; off >>= 1) {
        #pragma unroll
        for (int nn = 0; nn < 4; ++nn) {
            ps[nn] += __shfl_down(ps[nn], off);
            pd[nn] += __shfl_down(pd[nn], off);
        }
    }
    if ((tid & 63) == 0) {
        #pragma unroll
        for (int nn = 0; nn < 4; ++nn) {
            red[w][nn]     = ps[nn];
            red[w][4 + nn] = pd[nn];
        }
    }
    __syncthreads();

    #pragma unroll
    for (int nn = 0; nn < 4; ++nn) {
        float sum = (red[0][nn] + red[1][nn]) + (red[2][nn] + red[3][nn]);
        float dot = (red[0][4+nn] + red[1][4+nn]) + (red[2][4+nn] + red[3][4+nn]);
        float inv = 1.0f / sum;
        f32x4 av;
        av.x = ev[nn][0] * inv; av.y = ev[nn][1] * inv;
        av.z = ev[nn][2] * inv; av.w = ev[nn][3] * inv;
        f32x4* dst = (f32x4*)att + ((((nn * 12 + t) << 10) + i) << 8) + tid;
        __builtin_nontemporal_store(av, dst);
        if (tid == 0) out[((nn * 12 + t) << 10) + i] = dot * inv;
    }
}

extern "C" void kernel_launch(void* const* d_in, const int* in_sizes, int n_in,
                              void* d_out, int out_size, void* d_ws, size_t ws_size,
                              hipStream_t stream)
{
    const float* x      = (const float*)d_in[0];
    const float* conv0w = (const float*)d_in[1];  // (64,12,3,3)
    const float* convw  = (const float*)d_in[2];  // (4,64,64,3,3)
    const float* convb  = (const float*)d_in[3];  // (5,64)
    const float* gammas = (const float*)d_in[4];  // (5,64)
    const float* betas  = (const float*)d_in[5];  // (5,64)
    const float* regw   = (const float*)d_in[6];  // (12,64,3,3)
    const float* regb   = (const float*)d_in[7];  // (12)
    const float* attw   = (const float*)d_in[8];  // (12,1024,1024)

    float* out = (float*)d_out;                   // (4,12,32,32)
    float* att = out + 4 * 12 * 1024;             // (4,12,1024,1024)

    float* ws    = (float*)d_ws;
    float* stats = ws;                            // 5 x 128
    float* bufX  = stats + 640;                   // (48, 1224) padded input
    float* bufA  = bufX + 48 * PS;                // (256,1224) padded
    float* bufB  = bufA + 256 * PS;               // (256,1224) padded
    float* xf    = bufB + 256 * PS;               // (4,12,1024) flat

    // zero stats + all padded buffers (borders must be 0; ws is poisoned)
    (void)hipMemsetAsync(stats, 0,
                         (640 + 48 * PS + 2 * 256 * PS) * sizeof(float),
                         stream);

    pad_copy_kern<<<48, 256, 0, stream>>>(x, bufX);

    // conv0: 12 -> 64, raw input, accumulate stats0
    conv3x3_v2<12, 64, false, true, true><<<256, 256, 0, stream>>>(
        bufX, conv0w, convb, nullptr, nullptr, nullptr, bufA, stats);
    // conv1..4: 64 -> 64, BN(prev)+ReLU fused into input read
    conv3x3_v2<64, 64, true, true, true><<<256, 256, 0, stream>>>(
        bufA, convw + 0 * 36864, convb + 64, stats, gammas, betas,
        bufB, stats + 128);
    conv3x3_v2<64, 64, true, true, true><<<256, 256, 0, stream>>>(
        bufB, convw + 1 * 36864, convb + 128, stats + 128, gammas + 64,
        betas + 64, bufA, stats + 256);
    conv3x3_v2<64, 64, true, true, true><<<256, 256, 0, stream>>>(
        bufA, convw + 2 * 36864, convb + 192, stats + 256, gammas + 128,
        betas + 128, bufB, stats + 384);
    conv3x3_v2<64, 64, true, true, true><<<256, 256, 0, stream>>>(
        bufB, convw + 3 * 36864, convb + 256, stats + 384, gammas + 192,
        betas + 192, bufA, stats + 512);
    // regressor: 64 -> 12, BN(layer4)+ReLU on input, flat output
    conv3x3_v2<64, 12, true, false, false><<<48, 256, 0, stream>>>(
        bufA, regw, regb, stats + 512, gammas + 256, betas + 256, xf, nullptr);

    attention_v2<<<12288, 256, 0, stream>>>(xf, attw, out, att);
}